// Round 4
// baseline (5235.488 us; speedup 1.0000x reference)
//
#include <hip/hip_runtime.h>

typedef _Float16 f16;
typedef _Float16 f16x8 __attribute__((ext_vector_type(8)));
typedef float f32x16 __attribute__((ext_vector_type(16)));

__device__ __forceinline__ f16x8 zero8() {
  f16x8 v;
#pragma unroll
  for (int j = 0; j < 8; ++j) v[j] = (f16)0.f;
  return v;
}

__device__ __forceinline__ f16x8 cvt8p(const float* p) {
  float4 a = *(const float4*)p;
  float4 b = *(const float4*)(p + 4);
  f16x8 v;
  v[0] = (f16)a.x; v[1] = (f16)a.y; v[2] = (f16)a.z; v[3] = (f16)a.w;
  v[4] = (f16)b.x; v[5] = (f16)b.y; v[6] = (f16)b.z; v[7] = (f16)b.w;
  return v;
}

__device__ __forceinline__ void gload16(const void* g, void* l) {
  __builtin_amdgcn_global_load_lds((const __attribute__((address_space(1))) unsigned int*)g,
                                   (__attribute__((address_space(3))) unsigned int*)l, 16, 0, 0);
}

__device__ __forceinline__ float sigm(float x) {
  return __builtin_amdgcn_rcpf(1.f + __expf(-x));
}
__device__ __forceinline__ float tanh_(float x) {
  x = fminf(15.f, fmaxf(-15.f, x));
  float e = __expf(2.f * x);
  return 1.f - 2.f * __builtin_amdgcn_rcpf(e + 1.f);
}

// ---------------- small utility kernels ----------------

__global__ void k_cvt8(const float* __restrict__ x, f16* __restrict__ y, long n) {
  long i = ((long)blockIdx.x * blockDim.x + threadIdx.x) * 8;
  long stride = (long)gridDim.x * blockDim.x * 8;
  for (; i < n; i += stride) *(f16x8*)(y + i) = cvt8p(x + i);
}

// k_gru weight image: per (cg,chunk) region of 55296B = 384 rows x 144B.
// Row R = side*192 + cg2*96 + gate*32 + trow; within row, k-group kg (8 f16)
// lives at slot (kg + ((R>>3)&3)) & 7 (slot 8 = pad) -> conflict-free b128 reads.
__global__ void k_wc2(const float* __restrict__ Wih, const float* __restrict__ W,
                      unsigned char* __restrict__ dstb) {
  int j = blockIdx.x;   // 0..767 = gate*256 + hcol
  int k = threadIdx.x;  // 0..255
  float s = 0.f;
  for (int c = 0; c < 256; ++c) s = fmaf(Wih[j * 256 + c], W[c * 256 + k], s);
  int g = j >> 8, hcol = j & 255;
  int cg = hcol >> 6, cg2 = (hcol >> 5) & 1, trow = hcol & 31;
  int chunk = k >> 6, kl = k & 63;
  int R = cg2 * 96 + g * 32 + trow;  // side 0 (gi)
  int slot = ((kl >> 3) + ((R >> 3) & 3)) & 7;
  size_t byte = (size_t)(cg * 4 + chunk) * 55296 + (size_t)R * 144 + slot * 16 + (kl & 7) * 2;
  *(f16*)(dstb + byte) = (f16)s;
}

__global__ void k_whh2(const float* __restrict__ Whh, unsigned char* __restrict__ dstb) {
  int j = blockIdx.x;
  int k = threadIdx.x;
  float s = Whh[j * 256 + k];
  int g = j >> 8, hcol = j & 255;
  int cg = hcol >> 6, cg2 = (hcol >> 5) & 1, trow = hcol & 31;
  int chunk = k >> 6, kl = k & 63;
  int R = 192 + cg2 * 96 + g * 32 + trow;  // side 1 (gh)
  int slot = ((kl >> 3) + ((R >> 3) & 3)) & 7;
  size_t byte = (size_t)(cg * 4 + chunk) * 55296 + (size_t)R * 144 + slot * 16 + (kl & 7) * 2;
  *(f16*)(dstb + byte) = (f16)s;
}

// k_fn weight image: per chunk region of 69632B = 256 rows x 272B;
// kg (16 slots of data + 1 pad) at slot (kg + ((R>>3)&3)) & 15.
__global__ void k_prepw(const float* __restrict__ w, unsigned char* __restrict__ dstb) {
  int j = blockIdx.x;  // output col 0..255
  for (int k = threadIdx.x; k < 512; k += 256) {
    int chunk = k >> 7, kl = k & 127;
    int slot = ((kl >> 3) + ((j >> 3) & 3)) & 15;
    size_t byte = (size_t)chunk * 69632 + (size_t)j * 272 + slot * 16 + (kl & 7) * 2;
    *(f16*)(dstb + byte) = (f16)w[j * 512 + k];
  }
}

__global__ void k_v(const float* __restrict__ Wih, const float* __restrict__ b,
                    float* __restrict__ v) {
  int j = blockIdx.x * blockDim.x + threadIdx.x;
  if (j < 768) {
    float s = 0.f;
    for (int c = 0; c < 256; ++c) s = fmaf(Wih[j * 256 + c], b[c], s);
    v[j] = s;
  }
}

__global__ void k_hist(const int* __restrict__ dst, int* __restrict__ cnt, int E) {
  int e = blockIdx.x * 256 + threadIdx.x;
  if (e < E) atomicAdd(&cnt[dst[e]], 1);
}

__global__ void k_scan1(const int* __restrict__ deg, int* __restrict__ rowptr,
                        int* __restrict__ bsum, int n) {
  __shared__ int buf[256];
  int i = blockIdx.x * 256 + threadIdx.x;
  int v = (i < n) ? deg[i] : 0;
  buf[threadIdx.x] = v;
  __syncthreads();
  for (int off = 1; off < 256; off <<= 1) {
    int t = 0;
    if ((int)threadIdx.x >= off) t = buf[threadIdx.x - off];
    __syncthreads();
    buf[threadIdx.x] += t;
    __syncthreads();
  }
  if (i < n) rowptr[i] = buf[threadIdx.x] - v;
  if (threadIdx.x == 255) bsum[blockIdx.x] = buf[255];
}

__global__ void k_scan2(int* __restrict__ bsum, int nb) {
  __shared__ int buf[1024];
  int v = ((int)threadIdx.x < nb) ? bsum[threadIdx.x] : 0;
  buf[threadIdx.x] = v;
  __syncthreads();
  for (int off = 1; off < 1024; off <<= 1) {
    int t = 0;
    if ((int)threadIdx.x >= off) t = buf[threadIdx.x - off];
    __syncthreads();
    buf[threadIdx.x] += t;
    __syncthreads();
  }
  if ((int)threadIdx.x < nb) bsum[threadIdx.x] = buf[threadIdx.x] - v;
}

__global__ void k_scan3(int* __restrict__ rowptr, const int* __restrict__ bsum,
                        int n, int E) {
  int i = blockIdx.x * 256 + threadIdx.x;
  if (i < n) rowptr[i] += bsum[blockIdx.x];
  if (i == n) rowptr[n] = E;
}

__global__ void k_fill(const int* __restrict__ src, const int* __restrict__ dst,
                       const int* __restrict__ rowptr, int* __restrict__ cnt,
                       int* __restrict__ esrc, int E) {
  int e = blockIdx.x * 256 + threadIdx.x;
  if (e < E) {
    int d = dst[e];
    int r = atomicAdd(&cnt[d], 1);
    esrc[rowptr[d] + r] = src[e];
  }
}

__global__ void k_gather(const f16* __restrict__ h, const int* __restrict__ rowptr,
                         const int* __restrict__ esrc, f16* __restrict__ ag, int n) {
  int g = threadIdx.x >> 5, l = threadIdx.x & 31;
  int node = blockIdx.x * 8 + g;
  if (node >= n) return;
  int e0 = rowptr[node], e1 = rowptr[node + 1];
  float acc[8];
#pragma unroll
  for (int j = 0; j < 8; ++j) acc[j] = 0.f;
  for (int e = e0; e < e1; ++e) {
    int s = esrc[e];
    f16x8 hv = *(const f16x8*)(h + (long)s * 256 + l * 8);
#pragma unroll
    for (int j = 0; j < 8; ++j) acc[j] += (float)hv[j];
  }
  f16x8 o;
#pragma unroll
  for (int j = 0; j < 8; ++j) o[j] = (f16)acc[j];
  *(f16x8*)(ag + (long)node * 256 + l * 8) = o;
}

// ---------------- fused GRU kernel v3 ----------------
// Block = 256 rows x (cg: 64 h-cols). 8 waves = 4 row-supers(64) x 2 col-halves(32).
// Each wave computes BOTH gi and gh for its rows x cols -> wave-local epilogue.
// B (both weight mats) double-buffered in LDS, 144B-stride rotated-slot layout
// (conflict-free ds_read_b128); each B-frag reused for 2 row-groups.
__global__ __launch_bounds__(512, 2) void k_gru(
    const f16* __restrict__ ag, const f16* __restrict__ hin,
    const unsigned char* __restrict__ wprep, const float* __restrict__ bih,
    const float* __restrict__ bhh, const float* __restrict__ vv,
    const int* __restrict__ rowptr, f16* __restrict__ hout, int n) {
  __shared__ unsigned char SM[144384];
  f16* Xs = (f16*)(SM + 110592);           // [256][64] h_old / h' slice
  float* Ds = (float*)(SM + 110592 + 32768);  // deg[256]
  int bx = blockIdx.x;
  int rt = bx >> 2, cg = bx & 3;
  int row0 = rt * 256;
  int tid = threadIdx.x, lane = tid & 63, wid = tid >> 6;
  int l31 = lane & 31, hi = lane >> 5;
  int rs = wid >> 1, cg2 = wid & 1;
  const unsigned char* wb = wprep + (size_t)cg * 4 * 55296;

  // stage B chunk 0
  for (int i = wid; i < 54; i += 8) gload16(wb + i * 1024 + lane * 16, SM + i * 1024);

  // A fragments: [mat][rowgrp][ks] for a K-chunk of 64; double-buffered
  int arow[2];
  arow[0] = row0 + rs * 64 + l31;
  arow[1] = arow[0] + 32;
  f16x8 aA[2][2][4], aB[2][2][4];

  auto loadA = [&](f16x8(&dst)[2][2][4], int c) {
#pragma unroll
    for (int m = 0; m < 2; ++m) {
      const f16* mat = m ? hin : ag;
#pragma unroll
      for (int q = 0; q < 2; ++q) {
        bool ok = arow[q] < n;
        const f16* p = mat + (size_t)arow[q] * 256 + c * 64 + hi * 8;
#pragma unroll
        for (int ks = 0; ks < 4; ++ks)
          dst[m][q][ks] = ok ? *(const f16x8*)(p + ks * 16) : zero8();
      }
    }
  };
  loadA(aA, 0);

  // stage h_old slice + deg
  for (int e = tid; e < 2048; e += 512) {
    int r = e >> 3, q8 = e & 7;
    int grow = row0 + r;
    f16x8 v = (grow < n) ? *(const f16x8*)(hin + (size_t)grow * 256 + cg * 64 + q8 * 8)
                         : zero8();
    *(f16x8*)(Xs + r * 64 + q8 * 8) = v;
  }
  if (tid < 256) {
    int grow = row0 + tid;
    Ds[tid] = (grow < n) ? (float)(rowptr[grow + 1] - rowptr[grow]) : 0.f;
  }
  __syncthreads();

  f32x16 acc[2][3][2];  // [mat][gate][rowgrp]
#pragma unroll
  for (int m = 0; m < 2; ++m)
#pragma unroll
    for (int g = 0; g < 3; ++g)
#pragma unroll
      for (int q = 0; q < 2; ++q)
#pragma unroll
        for (int j = 0; j < 16; ++j) acc[m][g][q][j] = 0.f;

  int srot = (l31 >> 3) & 3;  // slot rotation (per-lane)

#pragma unroll
  for (int c = 0; c < 4; ++c) {
    if (c < 3) {
      const unsigned char* nb = wb + (size_t)(c + 1) * 55296;
      unsigned char* nd = SM + (size_t)((c + 1) & 1) * 55296;
      for (int i = wid; i < 54; i += 8) gload16(nb + i * 1024 + lane * 16, nd + i * 1024);
      if ((c + 1) & 1)
        loadA(aB, c + 1);
      else
        loadA(aA, c + 1);
    }
    const unsigned char* Bb = SM + (size_t)(c & 1) * 55296;
    const f16x8(&A)[2][2][4] = (c & 1) ? aB : aA;
#pragma unroll
    for (int ks = 0; ks < 4; ++ks) {
      int slot = ((ks * 2 + hi) + srot) & 7;
#pragma unroll
      for (int m = 0; m < 2; ++m) {
#pragma unroll
        for (int g = 0; g < 3; ++g) {
          int R = m * 192 + cg2 * 96 + g * 32 + l31;
          f16x8 b = *(const f16x8*)(Bb + R * 144 + slot * 16);
          acc[m][g][0] = __builtin_amdgcn_mfma_f32_32x32x16_f16(A[m][0][ks], b, acc[m][g][0], 0, 0, 0);
          acc[m][g][1] = __builtin_amdgcn_mfma_f32_32x32x16_f16(A[m][1][ks], b, acc[m][g][1], 0, 0, 0);
        }
      }
    }
    __syncthreads();
  }

  // wave-local GRU epilogue: lane holds (rows crow(rg,hi), col l31) for all 6 tiles
  int colL = cg2 * 32 + l31;
  int gcol = cg * 64 + colL;
  float br = bih[gcol] + bhh[gcol];
  float bz = bih[256 + gcol] + bhh[256 + gcol];
  float bi_n = bih[512 + gcol], bh_n = bhh[512 + gcol];
  float vr = vv[gcol], vz = vv[256 + gcol], vn = vv[512 + gcol];
#pragma unroll
  for (int q = 0; q < 2; ++q) {
#pragma unroll
    for (int rg = 0; rg < 16; ++rg) {
      int lrow = rs * 64 + q * 32 + (rg & 3) + 8 * (rg >> 2) + 4 * hi;
      float dg = Ds[lrow];
      float r = sigm(acc[0][0][q][rg] + acc[1][0][q][rg] + br + dg * vr);
      float z = sigm(acc[0][1][q][rg] + acc[1][1][q][rg] + bz + dg * vz);
      float xn = acc[0][2][q][rg] + bi_n + dg * vn + r * (acc[1][2][q][rg] + bh_n);
      float nn = tanh_(xn);
      float hold = (float)Xs[lrow * 64 + colL];
      Xs[lrow * 64 + colL] = (f16)((1.f - z) * nn + z * hold);
    }
  }
  __syncthreads();

  // coalesced copy-out of the block's 64-col slice
  for (int e = tid; e < 2048; e += 512) {
    int r = e >> 3, q8 = e & 7;
    int grow = row0 + r;
    if (grow < n)
      *(f16x8*)(hout + (size_t)grow * 256 + cg * 64 + q8 * 8) =
          *(const f16x8*)(Xs + r * 64 + q8 * 8);
  }
}

// ---------------- fused concat-linear v3: out = [hb | base] @ w^T + bias --------
// Block = 128 rows x 256 cols, K=512 in 4 chunks of 128. 8 waves = 2 rs x 4 cgf;
// wave = 64 rows x 64 cols (B-frag reused x2). Conflict-free 272B-stride layout.
__global__ __launch_bounds__(512, 4) void k_fn(
    const f16* __restrict__ hb, const float* __restrict__ base,
    const unsigned char* __restrict__ wp, const float* __restrict__ bias,
    float* __restrict__ out, int n) {
  __shared__ unsigned char SM[69632];
  int row0 = blockIdx.x * 128;
  int tid = threadIdx.x, lane = tid & 63, wid = tid >> 6;
  int l31 = lane & 31, hi = lane >> 5;
  int rs = wid >> 2, cgf = wid & 3;
  int arow[2];
  arow[0] = row0 + rs * 64 + l31;
  arow[1] = arow[0] + 32;
  int srot = (l31 >> 3) & 3;

  f32x16 acc[2][2];  // [rowgrp][tile]
#pragma unroll
  for (int q = 0; q < 2; ++q)
#pragma unroll
    for (int t = 0; t < 2; ++t)
#pragma unroll
      for (int j = 0; j < 16; ++j) acc[q][t][j] = 0.f;

#pragma unroll
  for (int c = 0; c < 4; ++c) {
    if (c) __syncthreads();
    for (int i = wid; i < 68; i += 8)
      gload16(wp + (size_t)c * 69632 + i * 1024 + lane * 16, SM + i * 1024);
    f16x8 areg[2][8];
#pragma unroll
    for (int q = 0; q < 2; ++q) {
      bool ok = arow[q] < n;
#pragma unroll
      for (int ks = 0; ks < 8; ++ks) {
        int k = c * 128 + ks * 16 + hi * 8;
        if (!ok)
          areg[q][ks] = zero8();
        else if (k < 256)
          areg[q][ks] = *(const f16x8*)(hb + (size_t)arow[q] * 256 + k);
        else
          areg[q][ks] = cvt8p(base + (size_t)arow[q] * 256 + (k - 256));
      }
    }
    __syncthreads();
#pragma unroll
    for (int ks = 0; ks < 8; ++ks) {
      int slot = ((ks * 2 + hi) + srot) & 15;
#pragma unroll
      for (int t = 0; t < 2; ++t) {
        int R = cgf * 64 + t * 32 + l31;
        f16x8 b = *(const f16x8*)(SM + R * 272 + slot * 16);
        acc[0][t] = __builtin_amdgcn_mfma_f32_32x32x16_f16(areg[0][ks], b, acc[0][t], 0, 0, 0);
        acc[1][t] = __builtin_amdgcn_mfma_f32_32x32x16_f16(areg[1][ks], b, acc[1][t], 0, 0, 0);
      }
    }
  }

#pragma unroll
  for (int t = 0; t < 2; ++t) {
    int col = cgf * 64 + t * 32 + l31;
    float bb = bias[col];
#pragma unroll
    for (int q = 0; q < 2; ++q) {
#pragma unroll
      for (int rg = 0; rg < 16; ++rg) {
        int grow = row0 + rs * 64 + q * 32 + (rg & 3) + 8 * (rg >> 2) + 4 * hi;
        if (grow < n) out[(size_t)grow * 256 + col] = acc[q][t][rg] + bb;
      }
    }
  }
}

// ---------------- launch ----------------
extern "C" void kernel_launch(void* const* d_in, const int* in_sizes, int n_in,
                              void* d_out, int out_size, void* d_ws, size_t ws_size,
                              hipStream_t stream) {
  const float* nodes = (const float*)d_in[0];
  const int* asrc = (const int*)d_in[1];
  const int* adst = (const int*)d_in[2];
  const int* csrc = (const int*)d_in[3];
  const int* cdst = (const int*)d_in[4];
  const float* W_ast = (const float*)d_in[5];
  const float* b_ast = (const float*)d_in[6];
  const float* Wih_a = (const float*)d_in[7];
  const float* Whh_a = (const float*)d_in[8];
  const float* bih_a = (const float*)d_in[9];
  const float* bhh_a = (const float*)d_in[10];
  const float* w1 = (const float*)d_in[11];
  const float* b1 = (const float*)d_in[12];
  const float* W_cpg = (const float*)d_in[13];
  const float* b_cpg = (const float*)d_in[14];
  const float* Wih_c = (const float*)d_in[15];
  const float* Whh_c = (const float*)d_in[16];
  const float* bih_c = (const float*)d_in[17];
  const float* bhh_c = (const float*)d_in[18];
  const float* w2 = (const float*)d_in[19];
  const float* b2 = (const float*)d_in[20];
  float* out = (float*)d_out;

  const int N = in_sizes[0] / 256;  // 150000
  const int EA = in_sizes[1];       // 300000
  const int EC = in_sizes[3];       // 250000
  const long ND = (long)N * 256;

  char* ws = (char*)d_ws;
  size_t off = 0;
  auto carve = [&](size_t bytes) -> char* {
    char* p = ws + off;
    off += (bytes + 255) & ~(size_t)255;
    return p;
  };
  f16* h0 = (f16*)carve(ND * 2);
  f16* h1 = (f16*)carve(ND * 2);
  f16* ag = (f16*)carve(ND * 2);
  unsigned char* wpA = (unsigned char*)carve(884736);  // 16 regions x 55296B
  unsigned char* wpC = (unsigned char*)carve(884736);
  unsigned char* w1p = (unsigned char*)carve(278528);  // 4 chunks x 69632B
  unsigned char* w2p = (unsigned char*)carve(278528);
  float* vA = (float*)carve(768 * 4);
  float* vC = (float*)carve(768 * 4);
  int* rowptr = (int*)carve((size_t)(N + 1) * 4);
  int* cnt = (int*)carve((size_t)N * 4);
  int* esrc = (int*)carve((size_t)(EA > EC ? EA : EC) * 4);
  int* bsum = (int*)carve(1024 * 4);
  (void)ws_size; (void)n_in; (void)out_size;

  const int GBLK = (N + 255) / 256;  // 586 row-blocks for k_gru
  const int FBLK = (N + 127) / 128;  // 1172 for k_fn
  const int SBLK = (N + 255) / 256;  // 586 for scans
  auto cvt = [&](const float* x, f16* y, long n) {
    int blocks = (int)((n / 8 + 255) / 256);
    if (blocks > 2048) blocks = 2048;
    k_cvt8<<<blocks, 256, 0, stream>>>(x, y, n);
  };

  // weight prep (conflict-free LDS images)
  k_wc2<<<768, 256, 0, stream>>>(Wih_a, W_ast, wpA);
  k_wc2<<<768, 256, 0, stream>>>(Wih_c, W_cpg, wpC);
  k_whh2<<<768, 256, 0, stream>>>(Whh_a, wpA);
  k_whh2<<<768, 256, 0, stream>>>(Whh_c, wpC);
  k_prepw<<<256, 256, 0, stream>>>(w1, w1p);
  k_prepw<<<256, 256, 0, stream>>>(w2, w2p);
  k_v<<<3, 256, 0, stream>>>(Wih_a, b_ast, vA);
  k_v<<<3, 256, 0, stream>>>(Wih_c, b_cpg, vC);
  cvt(nodes, h0, ND);

  auto run_branch = [&](const int* src, const int* dst, int E, const unsigned char* wprep,
                        const float* bih, const float* bhh, const float* v) {
    hipMemsetAsync(cnt, 0, (size_t)N * 4, stream);
    k_hist<<<(E + 255) / 256, 256, 0, stream>>>(dst, cnt, E);
    k_scan1<<<SBLK, 256, 0, stream>>>(cnt, rowptr, bsum, N);
    k_scan2<<<1, 1024, 0, stream>>>(bsum, SBLK);
    k_scan3<<<SBLK, 256, 0, stream>>>(rowptr, bsum, N, E);
    hipMemsetAsync(cnt, 0, (size_t)N * 4, stream);
    k_fill<<<(E + 255) / 256, 256, 0, stream>>>(src, dst, rowptr, cnt, esrc, E);
    k_gather<<<(N + 7) / 8, 256, 0, stream>>>(h0, rowptr, esrc, ag, N);
    k_gru<<<GBLK * 4, 512, 0, stream>>>(ag, h0, wprep, bih, bhh, v, rowptr, h1, N);
    k_gather<<<(N + 7) / 8, 256, 0, stream>>>(h1, rowptr, esrc, ag, N);
    k_gru<<<GBLK * 4, 512, 0, stream>>>(ag, h1, wprep, bih, bhh, v, rowptr, h0, N);
  };

  run_branch(asrc, adst, EA, wpA, bih_a, bhh_a, vA);
  k_fn<<<FBLK, 512, 0, stream>>>(h0, nodes, w1p, b1, out, N);
  cvt(out, h0, ND);
  run_branch(csrc, cdst, EC, wpC, bih_c, bhh_c, vC);
  k_fn<<<FBLK, 512, 0, stream>>>(h0, out, w2p, b2, out, N);
}

// Round 6
// 2010.758 us; speedup vs baseline: 2.6037x; 2.6037x over previous
//
#include <hip/hip_runtime.h>

typedef _Float16 f16;
typedef _Float16 f16x8 __attribute__((ext_vector_type(8)));
typedef float f32x16 __attribute__((ext_vector_type(16)));

__device__ __forceinline__ f16x8 zero8() {
  f16x8 v;
#pragma unroll
  for (int j = 0; j < 8; ++j) v[j] = (f16)0.f;
  return v;
}

__device__ __forceinline__ f16x8 cvt8p(const float* p) {
  float4 a = *(const float4*)p;
  float4 b = *(const float4*)(p + 4);
  f16x8 v;
  v[0] = (f16)a.x; v[1] = (f16)a.y; v[2] = (f16)a.z; v[3] = (f16)a.w;
  v[4] = (f16)b.x; v[5] = (f16)b.y; v[6] = (f16)b.z; v[7] = (f16)b.w;
  return v;
}

__device__ __forceinline__ void gload16(const void* g, void* l) {
  __builtin_amdgcn_global_load_lds((const __attribute__((address_space(1))) unsigned int*)g,
                                   (__attribute__((address_space(3))) unsigned int*)l, 16, 0, 0);
}

__device__ __forceinline__ float sigm(float x) {
  return __builtin_amdgcn_rcpf(1.f + __expf(-x));
}
__device__ __forceinline__ float tanh_(float x) {
  x = fminf(15.f, fmaxf(-15.f, x));
  float e = __expf(2.f * x);
  return 1.f - 2.f * __builtin_amdgcn_rcpf(e + 1.f);
}

// ---------------- small utility kernels ----------------

__global__ void k_cvt8(const float* __restrict__ x, f16* __restrict__ y, long n) {
  long i = ((long)blockIdx.x * blockDim.x + threadIdx.x) * 8;
  long stride = (long)gridDim.x * blockDim.x * 8;
  for (; i < n; i += stride) *(f16x8*)(y + i) = cvt8p(x + i);
}

// k_gru weight image: per (cg,chunk) region of 55296B = 384 rows x 144B.
// Row R = side*192 + cg2*96 + gate*32 + trow; k-group kg (8 f16) at slot
// (kg + ((R>>3)&3)) & 7 (9th slot = pad) -> uniform-bank ds_read_b128.
__global__ void k_wc2(const float* __restrict__ Wih, const float* __restrict__ W,
                      unsigned char* __restrict__ dstb) {
  int j = blockIdx.x;   // 0..767 = gate*256 + hcol
  int k = threadIdx.x;  // 0..255
  float s = 0.f;
  for (int c = 0; c < 256; ++c) s = fmaf(Wih[j * 256 + c], W[c * 256 + k], s);
  int g = j >> 8, hcol = j & 255;
  int cg = hcol >> 6, cg2 = (hcol >> 5) & 1, trow = hcol & 31;
  int chunk = k >> 6, kl = k & 63;
  int R = cg2 * 96 + g * 32 + trow;  // side 0 (gi)
  int slot = ((kl >> 3) + ((R >> 3) & 3)) & 7;
  size_t byte = (size_t)(cg * 4 + chunk) * 55296 + (size_t)R * 144 + slot * 16 + (kl & 7) * 2;
  *(f16*)(dstb + byte) = (f16)s;
}

__global__ void k_whh2(const float* __restrict__ Whh, unsigned char* __restrict__ dstb) {
  int j = blockIdx.x;
  int k = threadIdx.x;
  float s = Whh[j * 256 + k];
  int g = j >> 8, hcol = j & 255;
  int cg = hcol >> 6, cg2 = (hcol >> 5) & 1, trow = hcol & 31;
  int chunk = k >> 6, kl = k & 63;
  int R = 192 + cg2 * 96 + g * 32 + trow;  // side 1 (gh)
  int slot = ((kl >> 3) + ((R >> 3) & 3)) & 7;
  size_t byte = (size_t)(cg * 4 + chunk) * 55296 + (size_t)R * 144 + slot * 16 + (kl & 7) * 2;
  *(f16*)(dstb + byte) = (f16)s;
}

// k_fn weight image: per chunk region of 69632B = 256 rows x 272B;
// kg at slot (kg + ((R>>3)&3)) & 15 (17th slot pad).
__global__ void k_prepw(const float* __restrict__ w, unsigned char* __restrict__ dstb) {
  int j = blockIdx.x;  // output col 0..255
  for (int k = threadIdx.x; k < 512; k += 256) {
    int chunk = k >> 7, kl = k & 127;
    int slot = ((kl >> 3) + ((j >> 3) & 3)) & 15;
    size_t byte = (size_t)chunk * 69632 + (size_t)j * 272 + slot * 16 + (kl & 7) * 2;
    *(f16*)(dstb + byte) = (f16)w[j * 512 + k];
  }
}

__global__ void k_v(const float* __restrict__ Wih, const float* __restrict__ b,
                    float* __restrict__ v) {
  int j = blockIdx.x * blockDim.x + threadIdx.x;
  if (j < 768) {
    float s = 0.f;
    for (int c = 0; c < 256; ++c) s = fmaf(Wih[j * 256 + c], b[c], s);
    v[j] = s;
  }
}

__global__ void k_hist(const int* __restrict__ dst, int* __restrict__ cnt, int E) {
  int e = blockIdx.x * 256 + threadIdx.x;
  if (e < E) atomicAdd(&cnt[dst[e]], 1);
}

__global__ void k_scan1(const int* __restrict__ deg, int* __restrict__ rowptr,
                        int* __restrict__ bsum, int n) {
  __shared__ int buf[256];
  int i = blockIdx.x * 256 + threadIdx.x;
  int v = (i < n) ? deg[i] : 0;
  buf[threadIdx.x] = v;
  __syncthreads();
  for (int off = 1; off < 256; off <<= 1) {
    int t = 0;
    if ((int)threadIdx.x >= off) t = buf[threadIdx.x - off];
    __syncthreads();
    buf[threadIdx.x] += t;
    __syncthreads();
  }
  if (i < n) rowptr[i] = buf[threadIdx.x] - v;
  if (threadIdx.x == 255) bsum[blockIdx.x] = buf[255];
}

__global__ void k_scan2(int* __restrict__ bsum, int nb) {
  __shared__ int buf[1024];
  int v = ((int)threadIdx.x < nb) ? bsum[threadIdx.x] : 0;
  buf[threadIdx.x] = v;
  __syncthreads();
  for (int off = 1; off < 1024; off <<= 1) {
    int t = 0;
    if ((int)threadIdx.x >= off) t = buf[threadIdx.x - off];
    __syncthreads();
    buf[threadIdx.x] += t;
    __syncthreads();
  }
  if ((int)threadIdx.x < nb) bsum[threadIdx.x] = buf[threadIdx.x] - v;
}

__global__ void k_scan3(int* __restrict__ rowptr, const int* __restrict__ bsum,
                        int n, int E) {
  int i = blockIdx.x * 256 + threadIdx.x;
  if (i < n) rowptr[i] += bsum[blockIdx.x];
  if (i == n) rowptr[n] = E;
}

__global__ void k_fill(const int* __restrict__ src, const int* __restrict__ dst,
                       const int* __restrict__ rowptr, int* __restrict__ cnt,
                       int* __restrict__ esrc, int E) {
  int e = blockIdx.x * 256 + threadIdx.x;
  if (e < E) {
    int d = dst[e];
    int r = atomicAdd(&cnt[d], 1);
    esrc[rowptr[d] + r] = src[e];
  }
}

__global__ void k_gather(const f16* __restrict__ h, const int* __restrict__ rowptr,
                         const int* __restrict__ esrc, f16* __restrict__ ag, int n) {
  int g = threadIdx.x >> 5, l = threadIdx.x & 31;
  int node = blockIdx.x * 8 + g;
  if (node >= n) return;
  int e0 = rowptr[node], e1 = rowptr[node + 1];
  float acc[8];
#pragma unroll
  for (int j = 0; j < 8; ++j) acc[j] = 0.f;
  for (int e = e0; e < e1; ++e) {
    int s = esrc[e];
    f16x8 hv = *(const f16x8*)(h + (long)s * 256 + l * 8);
#pragma unroll
    for (int j = 0; j < 8; ++j) acc[j] += (float)hv[j];
  }
  f16x8 o;
#pragma unroll
  for (int j = 0; j < 8; ++j) o[j] = (f16)acc[j];
  *(f16x8*)(ag + (long)node * 256 + l * 8) = o;
}

// ---------------- fused GRU kernel v5 ----------------
// Block = 128 rows x 64 cols (cg). 8 waves = side(2) x cg2(2) x rs(2).
// Wave: ONE matrix (side 0: gi from ag, side 1: gh from hin), 32 cols (cg2),
// 64 rows (rs; 2 row-groups) -> B-frag reuse x2, acc[3][2] (96 AGPR).
// A per-chunk in statically-named ping-pong buffers a0/a1 (no cond refs!).
// Symmetric epilogue: side0 handles rowgroup 0, side1 rowgroup 1 (3-tile swap).
__global__ __launch_bounds__(512, 2) void k_gru(
    const f16* __restrict__ ag, const f16* __restrict__ hin,
    const unsigned char* __restrict__ wprep, const float* __restrict__ bih,
    const float* __restrict__ bhh, const float* __restrict__ vv,
    const int* __restrict__ rowptr, f16* __restrict__ hout, int n) {
  __shared__ unsigned char SM[110592 + 18432 + 512];
  f16* Xs = (f16*)(SM + 110592);              // [128][72] h_old / h' (144B stride)
  float* Ds = (float*)(SM + 110592 + 18432);  // deg[128]
  int bx = blockIdx.x;
  int rt = bx >> 2, cg = bx & 3;
  int row0 = rt * 128;
  int tid = threadIdx.x, lane = tid & 63, wid = tid >> 6;
  int l31 = lane & 31, hi = lane >> 5;
  int side = wid >> 2, w2 = wid & 3;
  int cg2 = w2 >> 1, rs = w2 & 1;
  const unsigned char* wb = wprep + (size_t)cg * 4 * 55296;
  int sb = side * 192 + cg2 * 96;  // B row base
  int srot = (l31 >> 3) & 3;

  auto stage = [&](int c) {
    const unsigned char* s0 = wb + (size_t)c * 55296;
    unsigned char* d0 = SM + (size_t)(c & 1) * 55296;
    for (int i = wid; i < 54; i += 8) gload16(s0 + i * 1024 + lane * 16, d0 + i * 1024);
  };

  const f16* Amat = side ? hin : ag;
  int arow0 = row0 + rs * 64 + l31;
  int arow1 = arow0 + 32;
  bool ok0 = arow0 < n, ok1 = arow1 < n;

  auto loadA = [&](f16x8(&dst)[2][4], int c) {
    const f16* p0 = Amat + (size_t)arow0 * 256 + c * 64 + hi * 8;
    const f16* p1 = Amat + (size_t)arow1 * 256 + c * 64 + hi * 8;
#pragma unroll
    for (int ks = 0; ks < 4; ++ks) {
      dst[0][ks] = ok0 ? *(const f16x8*)(p0 + ks * 16) : zero8();
      dst[1][ks] = ok1 ? *(const f16x8*)(p1 + ks * 16) : zero8();
    }
  };

  f32x16 acc[3][2];
#pragma unroll
  for (int g = 0; g < 3; ++g)
#pragma unroll
    for (int q = 0; q < 2; ++q)
#pragma unroll
      for (int j = 0; j < 16; ++j) acc[g][q][j] = 0.f;

  auto runC = [&](const f16x8(&A)[2][4], const unsigned char* Bb) {
#pragma unroll
    for (int ks = 0; ks < 4; ++ks) {
      int slot = ((ks * 2 + hi) + srot) & 7;
#pragma unroll
      for (int g = 0; g < 3; ++g) {
        int R = sb + g * 32 + l31;
        f16x8 b = *(const f16x8*)(Bb + R * 144 + slot * 16);
        acc[g][0] = __builtin_amdgcn_mfma_f32_32x32x16_f16(A[0][ks], b, acc[g][0], 0, 0, 0);
        acc[g][1] = __builtin_amdgcn_mfma_f32_32x32x16_f16(A[1][ks], b, acc[g][1], 0, 0, 0);
      }
    }
  };

  f16x8 a0[2][4], a1[2][4];

  // prologue: stage B chunk0, load A chunk0, stage h_old + deg
  stage(0);
  loadA(a0, 0);
  for (int e = tid; e < 1024; e += 512) {
    int r = e >> 3, q8 = e & 7;
    int grow = row0 + r;
    f16x8 v = (grow < n) ? *(const f16x8*)(hin + (size_t)grow * 256 + cg * 64 + q8 * 8)
                         : zero8();
    *(f16x8*)(Xs + r * 72 + q8 * 8) = v;
  }
  if (tid < 128) {
    int grow = row0 + tid;
    Ds[tid] = (grow < n) ? (float)(rowptr[grow + 1] - rowptr[grow]) : 0.f;
  }
  __syncthreads();

  // c=0: compute buf0/a0, prefetch chunk1 -> buf1/a1
  stage(1); loadA(a1, 1);
  runC(a0, SM);
  __syncthreads();
  // c=1: compute buf1/a1, prefetch chunk2 -> buf0/a0
  stage(2); loadA(a0, 2);
  runC(a1, SM + 55296);
  __syncthreads();
  // c=2: compute buf0/a0, prefetch chunk3 -> buf1/a1
  stage(3); loadA(a1, 3);
  runC(a0, SM);
  __syncthreads();
  // c=3: compute buf1/a1
  runC(a1, SM + 55296);
  __syncthreads();

  // symmetric exchange: each wave ships the row-group it does NOT handle.
  // pair region p = w2 (24KB each): [0,12K) = gi tiles (q=1), [12K,24K) = gh tiles (q=0)
  float* Ex = (float*)(SM + (size_t)w2 * 24576);
  if (side == 0) {
#pragma unroll
    for (int g = 0; g < 3; ++g)
#pragma unroll
      for (int rg = 0; rg < 16; ++rg)
        Ex[g * 1024 + rg * 64 + lane] = acc[g][1][rg];
  } else {
#pragma unroll
    for (int g = 0; g < 3; ++g)
#pragma unroll
      for (int rg = 0; rg < 16; ++rg)
        Ex[3072 + g * 1024 + rg * 64 + lane] = acc[g][0][rg];
  }
  __syncthreads();

  {
    int colL = cg2 * 32 + l31;
    int gcol = cg * 64 + colL;
    float br = bih[gcol] + bhh[gcol];
    float bz = bih[256 + gcol] + bhh[256 + gcol];
    float bi_n = bih[512 + gcol], bh_n = bhh[512 + gcol];
    float vr = vv[gcol], vz = vv[256 + gcol], vn = vv[512 + gcol];
    int qrow = rs * 64 + side * 32;
#pragma unroll
    for (int rg = 0; rg < 16; ++rg) {
      int lrow = qrow + (rg & 3) + 8 * (rg >> 2) + 4 * hi;
      float dg = Ds[lrow];
      float gi_r, gi_z, gi_n, gh_r, gh_z, gh_n;
      if (side == 0) {
        gi_r = acc[0][0][rg]; gi_z = acc[1][0][rg]; gi_n = acc[2][0][rg];
        gh_r = Ex[3072 + 0 * 1024 + rg * 64 + lane];
        gh_z = Ex[3072 + 1 * 1024 + rg * 64 + lane];
        gh_n = Ex[3072 + 2 * 1024 + rg * 64 + lane];
      } else {
        gh_r = acc[0][1][rg]; gh_z = acc[1][1][rg]; gh_n = acc[2][1][rg];
        gi_r = Ex[0 * 1024 + rg * 64 + lane];
        gi_z = Ex[1 * 1024 + rg * 64 + lane];
        gi_n = Ex[2 * 1024 + rg * 64 + lane];
      }
      float r = sigm(gi_r + gh_r + br + dg * vr);
      float z = sigm(gi_z + gh_z + bz + dg * vz);
      float nn = tanh_(gi_n + bi_n + dg * vn + r * (gh_n + bh_n));
      float hold = (float)Xs[lrow * 72 + colL];
      Xs[lrow * 72 + colL] = (f16)((1.f - z) * nn + z * hold);
    }
  }
  __syncthreads();

  // coalesced copy-out of the block's 64-col slice
  for (int e = tid; e < 1024; e += 512) {
    int r = e >> 3, q8 = e & 7;
    int grow = row0 + r;
    if (grow < n)
      *(f16x8*)(hout + (size_t)grow * 256 + cg * 64 + q8 * 8) =
          *(const f16x8*)(Xs + r * 72 + q8 * 8);
  }
}

// ---------------- fused concat-linear v3: out = [hb | base] @ w^T + bias --------
// Block = 128 rows x 256 cols, K=512 in 4 chunks of 128. 8 waves = 2 rs x 4 cgf;
// wave = 64 rows x 64 cols (B-frag reused x2). Conflict-free 272B-stride layout.
__global__ __launch_bounds__(512, 2) void k_fn(
    const f16* __restrict__ hb, const float* __restrict__ base,
    const unsigned char* __restrict__ wp, const float* __restrict__ bias,
    float* __restrict__ out, int n) {
  __shared__ unsigned char SM[69632];
  int row0 = blockIdx.x * 128;
  int tid = threadIdx.x, lane = tid & 63, wid = tid >> 6;
  int l31 = lane & 31, hi = lane >> 5;
  int rs = wid >> 2, cgf = wid & 3;
  int arow[2];
  arow[0] = row0 + rs * 64 + l31;
  arow[1] = arow[0] + 32;
  int srot = (l31 >> 3) & 3;

  f32x16 acc[2][2];  // [rowgrp][tile]
#pragma unroll
  for (int q = 0; q < 2; ++q)
#pragma unroll
    for (int t = 0; t < 2; ++t)
#pragma unroll
      for (int j = 0; j < 16; ++j) acc[q][t][j] = 0.f;

#pragma unroll
  for (int c = 0; c < 4; ++c) {
    if (c) __syncthreads();
    for (int i = wid; i < 68; i += 8)
      gload16(wp + (size_t)c * 69632 + i * 1024 + lane * 16, SM + i * 1024);
    f16x8 areg[2][8];
#pragma unroll
    for (int q = 0; q < 2; ++q) {
      bool ok = arow[q] < n;
#pragma unroll
      for (int ks = 0; ks < 8; ++ks) {
        int k = c * 128 + ks * 16 + hi * 8;
        if (!ok)
          areg[q][ks] = zero8();
        else if (k < 256)
          areg[q][ks] = *(const f16x8*)(hb + (size_t)arow[q] * 256 + k);
        else
          areg[q][ks] = cvt8p(base + (size_t)arow[q] * 256 + (k - 256));
      }
    }
    __syncthreads();
#pragma unroll
    for (int ks = 0; ks < 8; ++ks) {
      int slot = ((ks * 2 + hi) + srot) & 15;
#pragma unroll
      for (int t = 0; t < 2; ++t) {
        int R = cgf * 64 + t * 32 + l31;
        f16x8 b = *(const f16x8*)(SM + R * 272 + slot * 16);
        acc[0][t] = __builtin_amdgcn_mfma_f32_32x32x16_f16(areg[0][ks], b, acc[0][t], 0, 0, 0);
        acc[1][t] = __builtin_amdgcn_mfma_f32_32x32x16_f16(areg[1][ks], b, acc[1][t], 0, 0, 0);
      }
    }
  }

#pragma unroll
  for (int t = 0; t < 2; ++t) {
    int col = cgf * 64 + t * 32 + l31;
    float bb = bias[col];
#pragma unroll
    for (int q = 0; q < 2; ++q) {
#pragma unroll
      for (int rg = 0; rg < 16; ++rg) {
        int grow = row0 + rs * 64 + q * 32 + (rg & 3) + 8 * (rg >> 2) + 4 * hi;
        if (grow < n) out[(size_t)grow * 256 + col] = acc[q][t][rg] + bb;
      }
    }
  }
}

// ---------------- launch ----------------
extern "C" void kernel_launch(void* const* d_in, const int* in_sizes, int n_in,
                              void* d_out, int out_size, void* d_ws, size_t ws_size,
                              hipStream_t stream) {
  const float* nodes = (const float*)d_in[0];
  const int* asrc = (const int*)d_in[1];
  const int* adst = (const int*)d_in[2];
  const int* csrc = (const int*)d_in[3];
  const int* cdst = (const int*)d_in[4];
  const float* W_ast = (const float*)d_in[5];
  const float* b_ast = (const float*)d_in[6];
  const float* Wih_a = (const float*)d_in[7];
  const float* Whh_a = (const float*)d_in[8];
  const float* bih_a = (const float*)d_in[9];
  const float* bhh_a = (const float*)d_in[10];
  const float* w1 = (const float*)d_in[11];
  const float* b1 = (const float*)d_in[12];
  const float* W_cpg = (const float*)d_in[13];
  const float* b_cpg = (const float*)d_in[14];
  const float* Wih_c = (const float*)d_in[15];
  const float* Whh_c = (const float*)d_in[16];
  const float* bih_c = (const float*)d_in[17];
  const float* bhh_c = (const float*)d_in[18];
  const float* w2 = (const float*)d_in[19];
  const float* b2 = (const float*)d_in[20];
  float* out = (float*)d_out;

  const int N = in_sizes[0] / 256;  // 150000
  const int EA = in_sizes[1];       // 300000
  const int EC = in_sizes[3];       // 250000
  const long ND = (long)N * 256;

  char* ws = (char*)d_ws;
  size_t off = 0;
  auto carve = [&](size_t bytes) -> char* {
    char* p = ws + off;
    off += (bytes + 255) & ~(size_t)255;
    return p;
  };
  f16* h0 = (f16*)carve(ND * 2);
  f16* h1 = (f16*)carve(ND * 2);
  f16* ag = (f16*)carve(ND * 2);
  unsigned char* wpA = (unsigned char*)carve(884736);  // 16 regions x 55296B
  unsigned char* wpC = (unsigned char*)carve(884736);
  unsigned char* w1p = (unsigned char*)carve(278528);  // 4 chunks x 69632B
  unsigned char* w2p = (unsigned char*)carve(278528);
  float* vA = (float*)carve(768 * 4);
  float* vC = (float*)carve(768 * 4);
  int* rowptr = (int*)carve((size_t)(N + 1) * 4);
  int* cnt = (int*)carve((size_t)N * 4);
  int* esrc = (int*)carve((size_t)(EA > EC ? EA : EC) * 4);
  int* bsum = (int*)carve(1024 * 4);
  (void)ws_size; (void)n_in; (void)out_size;

  const int GBLK = (N + 127) / 128;  // 1172 row-tiles
  const int SBLK = (N + 255) / 256;  // 586 for scans
  auto cvt = [&](const float* x, f16* y, long n) {
    int blocks = (int)((n / 8 + 255) / 256);
    if (blocks > 2048) blocks = 2048;
    k_cvt8<<<blocks, 256, 0, stream>>>(x, y, n);
  };

  // weight prep (conflict-free LDS images)
  k_wc2<<<768, 256, 0, stream>>>(Wih_a, W_ast, wpA);
  k_wc2<<<768, 256, 0, stream>>>(Wih_c, W_cpg, wpC);
  k_whh2<<<768, 256, 0, stream>>>(Whh_a, wpA);
  k_whh2<<<768, 256, 0, stream>>>(Whh_c, wpC);
  k_prepw<<<256, 256, 0, stream>>>(w1, w1p);
  k_prepw<<<256, 256, 0, stream>>>(w2, w2p);
  k_v<<<3, 256, 0, stream>>>(Wih_a, b_ast, vA);
  k_v<<<3, 256, 0, stream>>>(Wih_c, b_cpg, vC);
  cvt(nodes, h0, ND);

  auto run_branch = [&](const int* src, const int* dst, int E, const unsigned char* wprep,
                        const float* bih, const float* bhh, const float* v) {
    hipMemsetAsync(cnt, 0, (size_t)N * 4, stream);
    k_hist<<<(E + 255) / 256, 256, 0, stream>>>(dst, cnt, E);
    k_scan1<<<SBLK, 256, 0, stream>>>(cnt, rowptr, bsum, N);
    k_scan2<<<1, 1024, 0, stream>>>(bsum, SBLK);
    k_scan3<<<SBLK, 256, 0, stream>>>(rowptr, bsum, N, E);
    hipMemsetAsync(cnt, 0, (size_t)N * 4, stream);
    k_fill<<<(E + 255) / 256, 256, 0, stream>>>(src, dst, rowptr, cnt, esrc, E);
    k_gather<<<(N + 7) / 8, 256, 0, stream>>>(h0, rowptr, esrc, ag, N);
    k_gru<<<GBLK * 4, 512, 0, stream>>>(ag, h0, wprep, bih, bhh, v, rowptr, h1, N);
    k_gather<<<(N + 7) / 8, 256, 0, stream>>>(h1, rowptr, esrc, ag, N);
    k_gru<<<GBLK * 4, 512, 0, stream>>>(ag, h1, wprep, bih, bhh, v, rowptr, h0, N);
  };

  run_branch(asrc, adst, EA, wpA, bih_a, bhh_a, vA);
  k_fn<<<GBLK, 512, 0, stream>>>(h0, nodes, w1p, b1, out, N);
  cvt(out, h0, ND);
  run_branch(csrc, cdst, EC, wpC, bih_c, bhh_c, vC);
  k_fn<<<GBLK, 512, 0, stream>>>(h0, out, w2p, b2, out, N);
}

// Round 7
// 1846.653 us; speedup vs baseline: 2.8351x; 1.0889x over previous
//
#include <hip/hip_runtime.h>

typedef _Float16 f16;
typedef _Float16 f16x8 __attribute__((ext_vector_type(8)));
typedef float f32x16 __attribute__((ext_vector_type(16)));

__device__ __forceinline__ f16x8 zero8() {
  f16x8 v;
#pragma unroll
  for (int j = 0; j < 8; ++j) v[j] = (f16)0.f;
  return v;
}

__device__ __forceinline__ f16x8 cvt8p(const float* p) {
  float4 a = *(const float4*)p;
  float4 b = *(const float4*)(p + 4);
  f16x8 v;
  v[0] = (f16)a.x; v[1] = (f16)a.y; v[2] = (f16)a.z; v[3] = (f16)a.w;
  v[4] = (f16)b.x; v[5] = (f16)b.y; v[6] = (f16)b.z; v[7] = (f16)b.w;
  return v;
}

__device__ __forceinline__ void gload16(const void* g, void* l) {
  __builtin_amdgcn_global_load_lds((const __attribute__((address_space(1))) unsigned int*)g,
                                   (__attribute__((address_space(3))) unsigned int*)l, 16, 0, 0);
}

__device__ __forceinline__ float sigm(float x) {
  return __builtin_amdgcn_rcpf(1.f + __expf(-x));
}
__device__ __forceinline__ float tanh_(float x) {
  x = fminf(15.f, fmaxf(-15.f, x));
  float e = __expf(2.f * x);
  return 1.f - 2.f * __builtin_amdgcn_rcpf(e + 1.f);
}

// ---------------- small utility kernels ----------------

__global__ void k_cvt8(const float* __restrict__ x, f16* __restrict__ y, long n) {
  long i = ((long)blockIdx.x * blockDim.x + threadIdx.x) * 8;
  long stride = (long)gridDim.x * blockDim.x * 8;
  for (; i < n; i += stride) *(f16x8*)(y + i) = cvt8p(x + i);
}

// k_gru v7 weight image: [hb 8][kc 8][R 96][slot 8][8 f16]
// hb = hcol>>5; R = gate*32 + trow (trow = hcol&31). kc 0-3: Wc k=kc*64+kl;
// kc 4-7: Whh k=(kc-4)*64+kl. slot = (kl>>3) ^ (trow&7)  (attn-verified swizzle).
__global__ void k_wc2(const float* __restrict__ Wih, const float* __restrict__ W,
                      unsigned char* __restrict__ dstb) {
  int j = blockIdx.x;   // 0..767 = gate*256 + hcol
  int k = threadIdx.x;  // 0..255
  float s = 0.f;
  for (int c = 0; c < 256; ++c) s = fmaf(Wih[j * 256 + c], W[c * 256 + k], s);
  int g = j >> 8, hcol = j & 255;
  int hb = hcol >> 5, trow = hcol & 31;
  int kc = k >> 6, kl = k & 63;
  int slot = (kl >> 3) ^ (trow & 7);
  size_t byte = (size_t)hb * 98304 + (size_t)kc * 12288 +
                (size_t)(g * 32 + trow) * 128 + slot * 16 + (kl & 7) * 2;
  *(f16*)(dstb + byte) = (f16)s;
}

__global__ void k_whh2(const float* __restrict__ Whh, unsigned char* __restrict__ dstb) {
  int j = blockIdx.x;
  int k = threadIdx.x;
  float s = Whh[j * 256 + k];
  int g = j >> 8, hcol = j & 255;
  int hb = hcol >> 5, trow = hcol & 31;
  int kc = 4 + (k >> 6), kl = k & 63;
  int slot = (kl >> 3) ^ (trow & 7);
  size_t byte = (size_t)hb * 98304 + (size_t)kc * 12288 +
                (size_t)(g * 32 + trow) * 128 + slot * 16 + (kl & 7) * 2;
  *(f16*)(dstb + byte) = (f16)s;
}

// k_fn weight image (unchanged): per chunk region of 69632B = 256 rows x 272B;
// kg at slot (kg + ((R>>3)&3)) & 15 (17th slot pad).
__global__ void k_prepw(const float* __restrict__ w, unsigned char* __restrict__ dstb) {
  int j = blockIdx.x;  // output col 0..255
  for (int k = threadIdx.x; k < 512; k += 256) {
    int chunk = k >> 7, kl = k & 127;
    int slot = ((kl >> 3) + ((j >> 3) & 3)) & 15;
    size_t byte = (size_t)chunk * 69632 + (size_t)j * 272 + slot * 16 + (kl & 7) * 2;
    *(f16*)(dstb + byte) = (f16)w[j * 512 + k];
  }
}

__global__ void k_v(const float* __restrict__ Wih, const float* __restrict__ b,
                    float* __restrict__ v) {
  int j = blockIdx.x * blockDim.x + threadIdx.x;
  if (j < 768) {
    float s = 0.f;
    for (int c = 0; c < 256; ++c) s = fmaf(Wih[j * 256 + c], b[c], s);
    v[j] = s;
  }
}

__global__ void k_hist(const int* __restrict__ dst, int* __restrict__ cnt, int E) {
  int e = blockIdx.x * 256 + threadIdx.x;
  if (e < E) atomicAdd(&cnt[dst[e]], 1);
}

__global__ void k_scan1(const int* __restrict__ deg, int* __restrict__ rowptr,
                        int* __restrict__ bsum, int n) {
  __shared__ int buf[256];
  int i = blockIdx.x * 256 + threadIdx.x;
  int v = (i < n) ? deg[i] : 0;
  buf[threadIdx.x] = v;
  __syncthreads();
  for (int off = 1; off < 256; off <<= 1) {
    int t = 0;
    if ((int)threadIdx.x >= off) t = buf[threadIdx.x - off];
    __syncthreads();
    buf[threadIdx.x] += t;
    __syncthreads();
  }
  if (i < n) rowptr[i] = buf[threadIdx.x] - v;
  if (threadIdx.x == 255) bsum[blockIdx.x] = buf[255];
}

__global__ void k_scan2(int* __restrict__ bsum, int nb) {
  __shared__ int buf[1024];
  int v = ((int)threadIdx.x < nb) ? bsum[threadIdx.x] : 0;
  buf[threadIdx.x] = v;
  __syncthreads();
  for (int off = 1; off < 1024; off <<= 1) {
    int t = 0;
    if ((int)threadIdx.x >= off) t = buf[threadIdx.x - off];
    __syncthreads();
    buf[threadIdx.x] += t;
    __syncthreads();
  }
  if ((int)threadIdx.x < nb) bsum[threadIdx.x] = buf[threadIdx.x] - v;
}

__global__ void k_scan3(int* __restrict__ rowptr, const int* __restrict__ bsum,
                        int n, int E) {
  int i = blockIdx.x * 256 + threadIdx.x;
  if (i < n) rowptr[i] += bsum[blockIdx.x];
  if (i == n) rowptr[n] = E;
}

__global__ void k_fill(const int* __restrict__ src, const int* __restrict__ dst,
                       const int* __restrict__ rowptr, int* __restrict__ cnt,
                       int* __restrict__ esrc, int E) {
  int e = blockIdx.x * 256 + threadIdx.x;
  if (e < E) {
    int d = dst[e];
    int r = atomicAdd(&cnt[d], 1);
    esrc[rowptr[d] + r] = src[e];
  }
}

__global__ void k_gather(const f16* __restrict__ h, const int* __restrict__ rowptr,
                         const int* __restrict__ esrc, f16* __restrict__ ag, int n) {
  int g = threadIdx.x >> 5, l = threadIdx.x & 31;
  int node = blockIdx.x * 8 + g;
  if (node >= n) return;
  int e0 = rowptr[node], e1 = rowptr[node + 1];
  float acc[8];
#pragma unroll
  for (int j = 0; j < 8; ++j) acc[j] = 0.f;
  for (int e = e0; e < e1; ++e) {
    int s = esrc[e];
    f16x8 hv = *(const f16x8*)(h + (long)s * 256 + l * 8);
#pragma unroll
    for (int j = 0; j < 8; ++j) acc[j] += (float)hv[j];
  }
  f16x8 o;
#pragma unroll
  for (int j = 0; j < 8; ++j) o[j] = (f16)acc[j];
  *(f16x8*)(ag + (long)node * 256 + l * 8) = o;
}

// ---------------- fused GRU kernel v7 ----------------
// Concat-GEMM: gates = [ag | hin] (K=512) x [Wc | Whh]^T for 32 hcols, 3 gates.
// Block = 256 rows x 32 hcols; 8 waves x 32 rows each; B panel (96KB) staged
// ONCE in two 48KB halves (compute c0-3 overlaps staging c4-7); barrier-free
// K-loop; wave-local GRU epilogue (acc_i[3] + acc_h[3], h_old direct global).
// Bijective XCD swizzle: all 8 hcol-blocks of a row-panel -> same XCD (L2 reuse).
__global__ __launch_bounds__(512, 1) void k_gru(
    const f16* __restrict__ ag, const f16* __restrict__ hin,
    const unsigned char* __restrict__ wprep, const float* __restrict__ bih,
    const float* __restrict__ bhh, const float* __restrict__ vv,
    const int* __restrict__ rowptr, f16* __restrict__ hout, int n, int nper) {
  __shared__ unsigned char SM[98304 + 1024];
  float* Ds = (float*)(SM + 98304);  // deg[256]
  int bid = blockIdx.x;
  int w = (bid & 7) * nper + (bid >> 3);  // XCD x gets w in [x*nper,(x+1)*nper)
  int rt = w >> 3, hb = w & 7;
  int row0 = rt * 256;
  int tid = threadIdx.x, lane = tid & 63, wid = tid >> 6;
  int l31 = lane & 31, hi = lane >> 5;
  const unsigned char* wb = wprep + (size_t)hb * 98304;

  // stage half 1 (regions 0-3, Wc) + deg
  for (int i = wid; i < 48; i += 8) gload16(wb + i * 1024 + lane * 16, SM + i * 1024);
  if (tid < 256) {
    int grow = row0 + tid;
    Ds[tid] = (grow < n) ? (float)(rowptr[grow + 1] - rowptr[grow]) : 0.f;
  }

  int arow = row0 + wid * 32 + l31;
  bool aok = arow < n;
  const f16* agp = ag + (size_t)arow * 256 + hi * 8;
  const f16* hp = hin + (size_t)arow * 256 + hi * 8;

  auto loadA = [&](f16x8(&dst)[4], const f16* p, int koff) {
#pragma unroll
    for (int ks = 0; ks < 4; ++ks)
      dst[ks] = aok ? *(const f16x8*)(p + koff + ks * 16) : zero8();
  };
  int sl0 = l31 & 7;
  auto runC = [&](const f16x8(&A)[4], const unsigned char* Bb, f32x16* accm) {
#pragma unroll
    for (int ks = 0; ks < 4; ++ks) {
      int sl = (ks * 2 + hi) ^ sl0;
#pragma unroll
      for (int g = 0; g < 3; ++g) {
        f16x8 b = *(const f16x8*)(Bb + (g * 32 + l31) * 128 + sl * 16);
        accm[g] = __builtin_amdgcn_mfma_f32_32x32x16_f16(A[ks], b, accm[g], 0, 0, 0);
      }
    }
  };

  f32x16 acc[6];  // 0-2: gi (r,z,n), 3-5: gh
#pragma unroll
  for (int t = 0; t < 6; ++t)
#pragma unroll
    for (int j = 0; j < 16; ++j) acc[t][j] = 0.f;

  f16x8 a0[4], a1[4];
  loadA(a0, agp, 0);
  __syncthreads();  // half-1 staged (drains gloads + our A c0 load is also done)

  // stage half 2 (regions 4-7, Whh) — overlapped with c0-c3 compute
  for (int i = 48 + wid; i < 96; i += 8) gload16(wb + i * 1024 + lane * 16, SM + i * 1024);

  loadA(a1, agp, 64);
  runC(a0, SM, acc);                 // c0
  loadA(a0, agp, 128);
  runC(a1, SM + 12288, acc);         // c1
  loadA(a1, agp, 192);
  runC(a0, SM + 24576, acc);         // c2
  loadA(a0, hp, 0);
  runC(a1, SM + 36864, acc);         // c3
  __syncthreads();  // half-2 staged
  loadA(a1, hp, 64);
  runC(a0, SM + 49152, acc + 3);     // c4
  loadA(a0, hp, 128);
  runC(a1, SM + 61440, acc + 3);     // c5
  loadA(a1, hp, 192);
  runC(a0, SM + 73728, acc + 3);     // c6
  runC(a1, SM + 86016, acc + 3);     // c7

  // wave-local GRU epilogue. C layout: col = l31 (hcol), row = crow(rg,hi).
  int gcol = hb * 32 + l31;
  float br = bih[gcol] + bhh[gcol];
  float bz = bih[256 + gcol] + bhh[256 + gcol];
  float bi_n = bih[512 + gcol], bh_n = bhh[512 + gcol];
  float vr = vv[gcol], vz = vv[256 + gcol], vn = vv[512 + gcol];
  int wrow = wid * 32;

  float hold[16];
#pragma unroll
  for (int rg = 0; rg < 16; ++rg) {
    int grow = row0 + wrow + (rg & 3) + 8 * (rg >> 2) + 4 * hi;
    hold[rg] = (grow < n) ? (float)hin[(size_t)grow * 256 + gcol] : 0.f;
  }
#pragma unroll
  for (int rg = 0; rg < 16; ++rg) {
    int crow = (rg & 3) + 8 * (rg >> 2) + 4 * hi;
    int grow = row0 + wrow + crow;
    float dg = Ds[wrow + crow];
    float r = sigm(acc[0][rg] + acc[3][rg] + br + dg * vr);
    float z = sigm(acc[1][rg] + acc[4][rg] + bz + dg * vz);
    float nn = tanh_(acc[2][rg] + bi_n + dg * vn + r * (acc[5][rg] + bh_n));
    if (grow < n)
      hout[(size_t)grow * 256 + gcol] = (f16)((1.f - z) * nn + z * hold[rg]);
  }
}

// ---------------- fused concat-linear (unchanged): out = [hb | base] @ w^T + bias
__global__ __launch_bounds__(512, 2) void k_fn(
    const f16* __restrict__ hb, const float* __restrict__ base,
    const unsigned char* __restrict__ wp, const float* __restrict__ bias,
    float* __restrict__ out, int n) {
  __shared__ unsigned char SM[69632];
  int row0 = blockIdx.x * 128;
  int tid = threadIdx.x, lane = tid & 63, wid = tid >> 6;
  int l31 = lane & 31, hi = lane >> 5;
  int rs = wid >> 2, cgf = wid & 3;
  int arow[2];
  arow[0] = row0 + rs * 64 + l31;
  arow[1] = arow[0] + 32;
  int srot = (l31 >> 3) & 3;

  f32x16 acc[2][2];  // [rowgrp][tile]
#pragma unroll
  for (int q = 0; q < 2; ++q)
#pragma unroll
    for (int t = 0; t < 2; ++t)
#pragma unroll
      for (int j = 0; j < 16; ++j) acc[q][t][j] = 0.f;

#pragma unroll
  for (int c = 0; c < 4; ++c) {
    if (c) __syncthreads();
    for (int i = wid; i < 68; i += 8)
      gload16(wp + (size_t)c * 69632 + i * 1024 + lane * 16, SM + i * 1024);
    f16x8 areg[2][8];
#pragma unroll
    for (int q = 0; q < 2; ++q) {
      bool ok = arow[q] < n;
#pragma unroll
      for (int ks = 0; ks < 8; ++ks) {
        int k = c * 128 + ks * 16 + hi * 8;
        if (!ok)
          areg[q][ks] = zero8();
        else if (k < 256)
          areg[q][ks] = *(const f16x8*)(hb + (size_t)arow[q] * 256 + k);
        else
          areg[q][ks] = cvt8p(base + (size_t)arow[q] * 256 + (k - 256));
      }
    }
    __syncthreads();
#pragma unroll
    for (int ks = 0; ks < 8; ++ks) {
      int slot = ((ks * 2 + hi) + srot) & 15;
#pragma unroll
      for (int t = 0; t < 2; ++t) {
        int R = cgf * 64 + t * 32 + l31;
        f16x8 b = *(const f16x8*)(SM + R * 272 + slot * 16);
        acc[0][t] = __builtin_amdgcn_mfma_f32_32x32x16_f16(areg[0][ks], b, acc[0][t], 0, 0, 0);
        acc[1][t] = __builtin_amdgcn_mfma_f32_32x32x16_f16(areg[1][ks], b, acc[1][t], 0, 0, 0);
      }
    }
  }

#pragma unroll
  for (int t = 0; t < 2; ++t) {
    int col = cgf * 64 + t * 32 + l31;
    float bb = bias[col];
#pragma unroll
    for (int q = 0; q < 2; ++q) {
#pragma unroll
      for (int rg = 0; rg < 16; ++rg) {
        int grow = row0 + rs * 64 + q * 32 + (rg & 3) + 8 * (rg >> 2) + 4 * hi;
        if (grow < n) out[(size_t)grow * 256 + col] = acc[q][t][rg] + bb;
      }
    }
  }
}

// ---------------- launch ----------------
extern "C" void kernel_launch(void* const* d_in, const int* in_sizes, int n_in,
                              void* d_out, int out_size, void* d_ws, size_t ws_size,
                              hipStream_t stream) {
  const float* nodes = (const float*)d_in[0];
  const int* asrc = (const int*)d_in[1];
  const int* adst = (const int*)d_in[2];
  const int* csrc = (const int*)d_in[3];
  const int* cdst = (const int*)d_in[4];
  const float* W_ast = (const float*)d_in[5];
  const float* b_ast = (const float*)d_in[6];
  const float* Wih_a = (const float*)d_in[7];
  const float* Whh_a = (const float*)d_in[8];
  const float* bih_a = (const float*)d_in[9];
  const float* bhh_a = (const float*)d_in[10];
  const float* w1 = (const float*)d_in[11];
  const float* b1 = (const float*)d_in[12];
  const float* W_cpg = (const float*)d_in[13];
  const float* b_cpg = (const float*)d_in[14];
  const float* Wih_c = (const float*)d_in[15];
  const float* Whh_c = (const float*)d_in[16];
  const float* bih_c = (const float*)d_in[17];
  const float* bhh_c = (const float*)d_in[18];
  const float* w2 = (const float*)d_in[19];
  const float* b2 = (const float*)d_in[20];
  float* out = (float*)d_out;

  const int N = in_sizes[0] / 256;  // 150000
  const int EA = in_sizes[1];       // 300000
  const int EC = in_sizes[3];       // 250000
  const long ND = (long)N * 256;

  char* ws = (char*)d_ws;
  size_t off = 0;
  auto carve = [&](size_t bytes) -> char* {
    char* p = ws + off;
    off += (bytes + 255) & ~(size_t)255;
    return p;
  };
  f16* h0 = (f16*)carve(ND * 2);
  f16* h1 = (f16*)carve(ND * 2);
  f16* ag = (f16*)carve(ND * 2);
  unsigned char* wpA = (unsigned char*)carve(786432);  // 8 hb x 8 kc x 12288B
  unsigned char* wpC = (unsigned char*)carve(786432);
  unsigned char* w1p = (unsigned char*)carve(278528);  // 4 chunks x 69632B
  unsigned char* w2p = (unsigned char*)carve(278528);
  float* vA = (float*)carve(768 * 4);
  float* vC = (float*)carve(768 * 4);
  int* rowptr = (int*)carve((size_t)(N + 1) * 4);
  int* cnt = (int*)carve((size_t)N * 4);
  int* esrc = (int*)carve((size_t)(EA > EC ? EA : EC) * 4);
  int* bsum = (int*)carve(1024 * 4);
  (void)ws_size; (void)n_in; (void)out_size;

  const int NRB = (N + 255) / 256;   // 586 row-panels
  const int FBLK = (N + 127) / 128;  // 1172 for k_fn
  const int SBLK = (N + 255) / 256;  // 586 for scans
  auto cvt = [&](const float* x, f16* y, long n) {
    int blocks = (int)((n / 8 + 255) / 256);
    if (blocks > 2048) blocks = 2048;
    k_cvt8<<<blocks, 256, 0, stream>>>(x, y, n);
  };

  // weight prep (conflict-free LDS images)
  k_wc2<<<768, 256, 0, stream>>>(Wih_a, W_ast, wpA);
  k_wc2<<<768, 256, 0, stream>>>(Wih_c, W_cpg, wpC);
  k_whh2<<<768, 256, 0, stream>>>(Whh_a, wpA);
  k_whh2<<<768, 256, 0, stream>>>(Whh_c, wpC);
  k_prepw<<<256, 256, 0, stream>>>(w1, w1p);
  k_prepw<<<256, 256, 0, stream>>>(w2, w2p);
  k_v<<<3, 256, 0, stream>>>(Wih_a, b_ast, vA);
  k_v<<<3, 256, 0, stream>>>(Wih_c, b_cpg, vC);
  cvt(nodes, h0, ND);

  auto run_branch = [&](const int* src, const int* dst, int E, const unsigned char* wprep,
                        const float* bih, const float* bhh, const float* v) {
    hipMemsetAsync(cnt, 0, (size_t)N * 4, stream);
    k_hist<<<(E + 255) / 256, 256, 0, stream>>>(dst, cnt, E);
    k_scan1<<<SBLK, 256, 0, stream>>>(cnt, rowptr, bsum, N);
    k_scan2<<<1, 1024, 0, stream>>>(bsum, SBLK);
    k_scan3<<<SBLK, 256, 0, stream>>>(rowptr, bsum, N, E);
    hipMemsetAsync(cnt, 0, (size_t)N * 4, stream);
    k_fill<<<(E + 255) / 256, 256, 0, stream>>>(src, dst, rowptr, cnt, esrc, E);
    k_gather<<<(N + 7) / 8, 256, 0, stream>>>(h0, rowptr, esrc, ag, N);
    k_gru<<<NRB * 8, 512, 0, stream>>>(ag, h0, wprep, bih, bhh, v, rowptr, h1, N, NRB);
    k_gather<<<(N + 7) / 8, 256, 0, stream>>>(h1, rowptr, esrc, ag, N);
    k_gru<<<NRB * 8, 512, 0, stream>>>(ag, h1, wprep, bih, bhh, v, rowptr, h0, N, NRB);
  };

  run_branch(asrc, adst, EA, wpA, bih_a, bhh_a, vA);
  k_fn<<<FBLK, 512, 0, stream>>>(h0, nodes, w1p, b1, out, N);
  cvt(out, h0, ND);
  run_branch(csrc, cdst, EC, wpC, bih_c, bhh_c, vC);
  k_fn<<<FBLK, 512, 0, stream>>>(h0, out, w2p, b2, out, N);
}